// Round 13
// baseline (614.636 us; speedup 1.0000x reference)
//
#include <hip/hip_runtime.h>
#include <hip/hip_bf16.h>
#include <cstddef>
#include <cstdint>

typedef unsigned short ushort_t;
typedef __attribute__((ext_vector_type(8))) short bf16x8;
typedef __attribute__((ext_vector_type(4))) float f32x4;

// ---------------- constants ----------------
#define H_ 256
#define NPT_ 1024
#define E_ 8192
#define K_ 48
#define L_ 3

// ws layout in floats (~31.3 MB peak)
#define WS_X      0u          // X fp32 [4][1024][256]; pacc sp3 during attn
#define WS_Y      1048576u    // conv GEMM accum / z2 after out-proj
#define WS_INT    2097152u    // int region
#define WS_CNTS   0u
#define WS_OFFS   49152u
#define WS_CUR    98352u
#define WS_ELIST  147504u
#define WS_M      2700288u    // Mhi/Mlo bf16 quarter (3145728 floats)
#define WS_QKV    2700288u    // pacc sp0-2 during attention
#define WS_WQ     5846016u    // conv W HALF hi/lo (1572864 floats)
#define WS_BF     5846016u    // bf16 Q/K/Vt post-conv (same region)
#define WS_PART   7418880u
#define WS_LOG    7435264u
#define WS_STATS  7439360u
#define WS_AW     7440000u    // attn_W hi/lo (262144 floats) -> 7702144
#define WS_PML    7702144u    // attn split l-sums -> 7833216

__device__ __forceinline__ ushort_t f2bf(float x) {
  unsigned u = __float_as_uint(x);
  unsigned r = (u + 0x7FFFu + ((u >> 16) & 1u)) >> 16;
  return (ushort_t)r;
}
__device__ __forceinline__ float bf2f(ushort_t x) {
  return __uint_as_float(((unsigned)x) << 16);
}
__device__ __forceinline__ ushort_t f2bf_rn(float x) {
  __hip_bfloat16 h = __float2bfloat16(x);
  return *reinterpret_cast<ushort_t*>(&h);
}
__device__ __forceinline__ unsigned pkbf(float a, float b) {
  return (unsigned)f2bf_rn(a) | ((unsigned)f2bf_rn(b) << 16);
}

// ---------------- proj ----------------
__global__ __launch_bounds__(256) void k_proj(const float* __restrict__ xn,
    const float* __restrict__ pW, const float* __restrict__ pb,
    float* __restrict__ x)
{
  const int t = blockIdx.x >> 10, n = blockIdx.x & 1023;
  const int tid = threadIdx.x;
  __shared__ float xr[32];
  if (tid < 21) xr[tid] = xn[(size_t)(t*1024 + n)*21 + tid];
  __syncthreads();
  float acc = pb[t*256 + tid];
  #pragma unroll
  for (int i = 0; i < 21; ++i) acc += xr[i] * pW[(size_t)(t*21 + i)*256 + tid];
  x[(size_t)(t*1024 + n)*256 + tid] = acc;
}

// ---------------- CSR build ----------------
__global__ __launch_bounds__(256) void k_hist(const int* __restrict__ ei, int* __restrict__ cnts)
{
  const int gid = blockIdx.x*256 + threadIdx.x;
  const int k = gid >> 13, e = gid & 8191;
  const int dst = ei[(size_t)k*2*E_ + E_ + e];
  atomicAdd(&cnts[k*1024 + dst], 1);
}

__global__ __launch_bounds__(1024) void k_scan(const int* __restrict__ cnts,
    int* __restrict__ offs, int* __restrict__ cur)
{
  const int k = blockIdx.x, tid = threadIdx.x;
  __shared__ int s[1024];
  const int v = cnts[k*1024 + tid];
  s[tid] = v; __syncthreads();
  for (int off = 1; off < 1024; off <<= 1) {
    int add = 0;
    if (tid >= off) add = s[tid - off];
    __syncthreads();
    s[tid] += add;
    __syncthreads();
  }
  const int ex = s[tid] - v;
  offs[k*1025 + tid] = ex;
  cur[k*1024 + tid] = ex;
  if (tid == 1023) offs[k*1025 + 1024] = s[1023];
}

__global__ __launch_bounds__(256) void k_scatter(const int* __restrict__ ei,
    int* __restrict__ cur, int* __restrict__ elist)
{
  const int gid = blockIdx.x*256 + threadIdx.x;
  const int k = gid >> 13, e = gid & 8191;
  const int src = ei[(size_t)k*2*E_ + e];
  const int dst = ei[(size_t)k*2*E_ + E_ + e];
  const int p = atomicAdd(&cur[k*1024 + dst], 1);
  elist[k*E_ + p] = src;
}

// ---------------- means ----------------
__global__ __launch_bounds__(256) void k_means(const float* __restrict__ X,
    const int* __restrict__ offs, const int* __restrict__ elist,
    ushort_t* __restrict__ Mhi, ushort_t* __restrict__ Mlo, int a)
{
  const int pid = blockIdx.x*4 + (threadIdx.x >> 6);
  const int kl = pid >> 10, d = pid & 1023;
  const int lane = threadIdx.x & 63;
  const int kg = a*12 + kl;
  const int o0 = offs[kg*1025 + d];
  const int o1 = offs[kg*1025 + d + 1];
  const float* xb = X + (size_t)a*1024*256;
  float4 s = {0.f, 0.f, 0.f, 0.f};
  int p = o0;
  while (p + 8 <= o1) {
    int srcs[8];
    #pragma unroll
    for (int q = 0; q < 8; ++q) srcs[q] = elist[(size_t)kg*E_ + p + q];
    float4 v[8];
    #pragma unroll
    for (int q = 0; q < 8; ++q)
      v[q] = *reinterpret_cast<const float4*>(xb + (size_t)srcs[q]*256 + lane*4);
    s.x += ((v[0].x+v[1].x)+(v[2].x+v[3].x)) + ((v[4].x+v[5].x)+(v[6].x+v[7].x));
    s.y += ((v[0].y+v[1].y)+(v[2].y+v[3].y)) + ((v[4].y+v[5].y)+(v[6].y+v[7].y));
    s.z += ((v[0].z+v[1].z)+(v[2].z+v[3].z)) + ((v[4].z+v[5].z)+(v[6].z+v[7].z));
    s.w += ((v[0].w+v[1].w)+(v[2].w+v[3].w)) + ((v[4].w+v[5].w)+(v[6].w+v[7].w));
    p += 8;
  }
  while (p + 4 <= o1) {
    const int s0 = elist[(size_t)kg*E_ + p + 0];
    const int s1 = elist[(size_t)kg*E_ + p + 1];
    const int s2 = elist[(size_t)kg*E_ + p + 2];
    const int s3 = elist[(size_t)kg*E_ + p + 3];
    const float4 v0 = *reinterpret_cast<const float4*>(xb + (size_t)s0*256 + lane*4);
    const float4 v1 = *reinterpret_cast<const float4*>(xb + (size_t)s1*256 + lane*4);
    const float4 v2 = *reinterpret_cast<const float4*>(xb + (size_t)s2*256 + lane*4);
    const float4 v3 = *reinterpret_cast<const float4*>(xb + (size_t)s3*256 + lane*4);
    s.x += (v0.x + v1.x) + (v2.x + v3.x);
    s.y += (v0.y + v1.y) + (v2.y + v3.y);
    s.z += (v0.z + v1.z) + (v2.z + v3.z);
    s.w += (v0.w + v1.w) + (v2.w + v3.w);
    p += 4;
  }
  while (p < o1) {
    const int sp = elist[(size_t)kg*E_ + p];
    const float4 v = *reinterpret_cast<const float4*>(xb + (size_t)sp*256 + lane*4);
    s.x += v.x; s.y += v.y; s.z += v.z; s.w += v.w;
    ++p;
  }
  const float inv = 1.f / fmaxf((float)(o1 - o0), 1.f);
  const float mv[4] = {s.x*inv, s.y*inv, s.z*inv, s.w*inv};
  ushort_t hi[4], lo[4];
  #pragma unroll
  for (int e = 0; e < 4; ++e) {
    hi[e] = f2bf(mv[e]);
    lo[e] = f2bf(mv[e] - bf2f(hi[e]));
  }
  const size_t base = ((size_t)kl*1024 + d)*256 + lane*4;
  *reinterpret_cast<ushort4*>(Mhi + base) = *reinterpret_cast<const ushort4*>(hi);
  *reinterpret_cast<ushort4*>(Mlo + base) = *reinterpret_cast<const ushort4*>(lo);
}

// ---------------- W prep: transpose + hi/lo split ----------------
// grid (nmat, 8, 8), block 256
__global__ __launch_bounds__(256) void k_wprep(const float* __restrict__ Wsrc,
    ushort_t* __restrict__ Whi, ushort_t* __restrict__ Wlo)
{
  const int kl = blockIdx.x, hb = blockIdx.y, gb = blockIdx.z;
  const int tid = threadIdx.x;
  __shared__ float tile[32][33];
  const float* W = Wsrc + (size_t)kl*65536;
  const int r0 = tid >> 5, c = tid & 31;
  #pragma unroll
  for (int it = 0; it < 4; ++it) {
    const int r = it*8 + r0;
    tile[r][c] = W[(size_t)(hb*32 + r)*256 + gb*32 + c];
  }
  __syncthreads();
  #pragma unroll
  for (int it = 0; it < 4; ++it) {
    const int g = it*8 + r0, h = c;
    const float v = tile[h][g];
    const ushort_t hi = f2bf(v);
    const ushort_t lo = f2bf(v - bf2f(hi));
    const size_t off = (size_t)kl*65536 + (size_t)(gb*32 + g)*256 + hb*32 + h;
    Whi[off] = hi;
    Wlo[off] = lo;
  }
}

// ---------------- conv GEMM ----------------
__global__ __launch_bounds__(256) void k_wxm(const ushort_t* __restrict__ Mhi,
    const ushort_t* __restrict__ Mlo, const ushort_t* __restrict__ Wqhi,
    const ushort_t* __restrict__ Wqlo, float* __restrict__ Y, int a)
{
  const int cb = blockIdx.x, rb = blockIdx.y, t = blockIdx.z;
  const int tid = threadIdx.x, wave = tid >> 6, lane = tid & 63;
  const int lrow = lane & 15, lgrp = lane >> 4;
  __shared__ __align__(16) ushort_t AswH[64*64];
  __shared__ __align__(16) ushort_t AswL[64*64];
  __shared__ __align__(16) ushort_t BswH[64*64];
  __shared__ __align__(16) ushort_t BswL[64*64];
  f32x4 acc[4];
  #pragma unroll
  for (int j = 0; j < 4; ++j) acc[j] = (f32x4){0.f,0.f,0.f,0.f};

  for (int c = 0; c < 3; ++c) {
    const int kl = t*3 + c;
    const ushort_t* Ah = Mhi + ((size_t)kl*1024 + rb*64)*256;
    const ushort_t* Al = Mlo + ((size_t)kl*1024 + rb*64)*256;
    const ushort_t* Bh = Wqhi + (size_t)kl*65536 + (size_t)cb*64*256;
    const ushort_t* Bl = Wqlo + (size_t)kl*65536 + (size_t)cb*64*256;
    for (int ks = 0; ks < 4; ++ks) {
      __syncthreads();
      #pragma unroll
      for (int it = 0; it < 2; ++it) {
        const int idx = tid + it*256;
        const int row = idx >> 3, c8 = idx & 7;
        const int off = row*64 + ((c8 ^ (row & 7)) << 3);
        const size_t gsrc = (size_t)row*256 + ks*64 + c8*8;
        *reinterpret_cast<bf16x8*>(&AswH[off]) = *reinterpret_cast<const bf16x8*>(Ah + gsrc);
        *reinterpret_cast<bf16x8*>(&AswL[off]) = *reinterpret_cast<const bf16x8*>(Al + gsrc);
        *reinterpret_cast<bf16x8*>(&BswH[off]) = *reinterpret_cast<const bf16x8*>(Bh + gsrc);
        *reinterpret_cast<bf16x8*>(&BswL[off]) = *reinterpret_cast<const bf16x8*>(Bl + gsrc);
      }
      __syncthreads();
      #pragma unroll
      for (int ksub = 0; ksub < 2; ++ksub) {
        const int c8 = ksub*4 + lgrp;
        const int arow = wave*16 + lrow;
        const int aoff = arow*64 + ((c8 ^ (arow & 7)) << 3);
        const bf16x8 ah = *reinterpret_cast<const bf16x8*>(&AswH[aoff]);
        const bf16x8 al = *reinterpret_cast<const bf16x8*>(&AswL[aoff]);
        #pragma unroll
        for (int nf = 0; nf < 4; ++nf) {
          const int g = nf*16 + lrow;
          const int boff = g*64 + ((c8 ^ (g & 7)) << 3);
          const bf16x8 bh = *reinterpret_cast<const bf16x8*>(&BswH[boff]);
          const bf16x8 bl = *reinterpret_cast<const bf16x8*>(&BswL[boff]);
          __builtin_amdgcn_s_setprio(1);
          acc[nf] = __builtin_amdgcn_mfma_f32_16x16x32_bf16(ah, bh, acc[nf], 0, 0, 0);
          acc[nf] = __builtin_amdgcn_mfma_f32_16x16x32_bf16(ah, bl, acc[nf], 0, 0, 0);
          acc[nf] = __builtin_amdgcn_mfma_f32_16x16x32_bf16(al, bh, acc[nf], 0, 0, 0);
          __builtin_amdgcn_s_setprio(0);
        }
      }
    }
  }
  float* Cb = Y + ((size_t)(t*1024 + rb*64))*256 + cb*64;
  #pragma unroll
  for (int nf = 0; nf < 4; ++nf)
    #pragma unroll
    for (int r = 0; r < 4; ++r) {
      const int row = wave*16 + lgrp*4 + r;
      const int col = nf*16 + lrow;
      if (a == 0) Cb[(size_t)row*256 + col] = acc[nf][r];
      else        Cb[(size_t)row*256 + col] += acc[nf][r];
    }
}

// ---------------- bias-gate + residual + LN + relu ----------------
__global__ __launch_bounds__(256) void k_ln(float* __restrict__ x,
    const float* __restrict__ y, const int* __restrict__ cnts,
    const float* __restrict__ convB, const float* __restrict__ ng,
    const float* __restrict__ nb, int l)
{
  const int r = blockIdx.x;
  const int t = r >> 10, d = r & 1023;
  const int tid = threadIdx.x;
  __shared__ float flag[12];
  __shared__ float rbuf[256];
  if (tid < 12) {
    const int a = tid / 3, c = tid - a*3;
    const int kj = a*12 + t*3 + c;
    flag[tid] = (cnts[kj*1024 + d] > 0) ? 1.f : 0.f;
  }
  __syncthreads();
  float v = y[(size_t)r*256 + tid] + x[(size_t)r*256 + tid];
  #pragma unroll
  for (int j = 0; j < 12; ++j) {
    const int a = j / 3, c = j - a*3;
    const int kj = a*12 + t*3 + c;
    v += flag[j] * convB[(size_t)(l*K_ + kj)*256 + tid];
  }
  rbuf[tid] = v; __syncthreads();
  for (int s = 128; s > 0; s >>= 1) { if (tid < s) rbuf[tid] += rbuf[tid+s]; __syncthreads(); }
  const float mean = rbuf[0] * (1.f/256.f); __syncthreads();
  const float diff = v - mean;
  rbuf[tid] = diff*diff; __syncthreads();
  for (int s = 128; s > 0; s >>= 1) { if (tid < s) rbuf[tid] += rbuf[tid+s]; __syncthreads(); }
  const float var = rbuf[0] * (1.f/256.f); __syncthreads();
  const float xn = diff * rsqrtf(var + 1e-5f) * ng[(size_t)(l*4 + t)*256 + tid]
                 + nb[(size_t)(l*4 + t)*256 + tid];
  x[(size_t)r*256 + tid] = fmaxf(xn, 0.f);
}

// ---------------- QKV GEMM with fused bf16 cast (Q scaled, V transposed) ----------------
// grid (6, 32), block 256
__global__ __launch_bounds__(256) void k_gemmq(const float* __restrict__ A,
    const ushort_t* __restrict__ Bh, const ushort_t* __restrict__ Bl,
    const float* __restrict__ bias,
    ushort_t* __restrict__ Qh, ushort_t* __restrict__ Kh, ushort_t* __restrict__ Vt)
{
  const int cb = blockIdx.x, rb = blockIdx.y;
  const int col0 = cb*128, i = col0 >> 8, g0 = col0 & 255;
  const int tid = threadIdx.x, wave = tid >> 6, lane = tid & 63;
  const int lrow = lane & 15, lgrp = lane >> 4;
  const int wr = wave >> 1, wc = wave & 1;
  __shared__ __align__(16) ushort_t AswH[128*64];
  __shared__ __align__(16) ushort_t AswL[128*64];
  __shared__ __align__(16) ushort_t BswH[128*64];
  __shared__ __align__(16) ushort_t BswL[128*64];
  const float* Ab = A + (size_t)rb*128*256;
  const ushort_t* Bhp = Bh + (size_t)i*65536 + (size_t)g0*256;
  const ushort_t* Blp = Bl + (size_t)i*65536 + (size_t)g0*256;
  f32x4 acc[4][4];
  #pragma unroll
  for (int m = 0; m < 4; ++m)
    #pragma unroll
    for (int n = 0; n < 4; ++n) acc[m][n] = (f32x4){0.f,0.f,0.f,0.f};

  for (int ks = 0; ks < 4; ++ks) {
    __syncthreads();
    #pragma unroll
    for (int it = 0; it < 8; ++it) {
      const int idx = tid + it*256;
      const int row = idx >> 4, c4 = idx & 15;
      const float4 v = *reinterpret_cast<const float4*>(Ab + (size_t)row*256 + ks*64 + c4*4);
      const float f[4] = {v.x, v.y, v.z, v.w};
      ushort_t hi[4], lo[4];
      #pragma unroll
      for (int e = 0; e < 4; ++e) {
        hi[e] = f2bf(f[e]);
        lo[e] = f2bf(f[e] - bf2f(hi[e]));
      }
      const int c8 = c4 >> 1, sub = (c4 & 1) * 4;
      const int off = row*64 + ((c8 ^ (row & 7)) << 3) + sub;
      *reinterpret_cast<uint2*>(&AswH[off]) = *reinterpret_cast<const uint2*>(hi);
      *reinterpret_cast<uint2*>(&AswL[off]) = *reinterpret_cast<const uint2*>(lo);
    }
    #pragma unroll
    for (int it = 0; it < 4; ++it) {
      const int idx = tid + it*256;
      const int row = idx >> 3, c8 = idx & 7;
      const int off = row*64 + ((c8 ^ (row & 7)) << 3);
      const size_t gsrc = (size_t)row*256 + ks*64 + c8*8;
      *reinterpret_cast<bf16x8*>(&BswH[off]) = *reinterpret_cast<const bf16x8*>(Bhp + gsrc);
      *reinterpret_cast<bf16x8*>(&BswL[off]) = *reinterpret_cast<const bf16x8*>(Blp + gsrc);
    }
    __syncthreads();
    #pragma unroll
    for (int ksub = 0; ksub < 2; ++ksub) {
      bf16x8 ah[4], al[4], bh[4], bl[4];
      const int c8 = ksub*4 + lgrp;
      #pragma unroll
      for (int mf = 0; mf < 4; ++mf) {
        const int row = wr*64 + mf*16 + lrow;
        const int off = row*64 + ((c8 ^ (row & 7)) << 3);
        ah[mf] = *reinterpret_cast<const bf16x8*>(&AswH[off]);
        al[mf] = *reinterpret_cast<const bf16x8*>(&AswL[off]);
      }
      #pragma unroll
      for (int nf = 0; nf < 4; ++nf) {
        const int row = wc*64 + nf*16 + lrow;
        const int off = row*64 + ((c8 ^ (row & 7)) << 3);
        bh[nf] = *reinterpret_cast<const bf16x8*>(&BswH[off]);
        bl[nf] = *reinterpret_cast<const bf16x8*>(&BswL[off]);
      }
      __builtin_amdgcn_s_setprio(1);
      #pragma unroll
      for (int mf = 0; mf < 4; ++mf)
        #pragma unroll
        for (int nf = 0; nf < 4; ++nf) {
          acc[mf][nf] = __builtin_amdgcn_mfma_f32_16x16x32_bf16(ah[mf], bh[nf], acc[mf][nf], 0, 0, 0);
          acc[mf][nf] = __builtin_amdgcn_mfma_f32_16x16x32_bf16(ah[mf], bl[nf], acc[mf][nf], 0, 0, 0);
          acc[mf][nf] = __builtin_amdgcn_mfma_f32_16x16x32_bf16(al[mf], bh[nf], acc[mf][nf], 0, 0, 0);
        }
      __builtin_amdgcn_s_setprio(0);
    }
  }
  const float* bp = bias + i*256;
  const float qs = (i == 0) ? 0.17677669529663687f : 1.f;
  #pragma unroll
  for (int mf = 0; mf < 4; ++mf)
    #pragma unroll
    for (int nf = 0; nf < 4; ++nf) {
      const int colg = g0 + wc*64 + nf*16 + lrow;
      const int h = colg >> 5, d = colg & 31;
      const float b = bp[colg];
      const int rowbase = rb*128 + wr*64 + mf*16 + lgrp*4;
      if (i < 2) {
        ushort_t* dst = (i == 0) ? Qh : Kh;
        #pragma unroll
        for (int r = 0; r < 4; ++r)
          dst[((size_t)(h*4096 + rowbase + r))*32 + d] = f2bf_rn((acc[mf][nf][r] + b) * qs);
      } else {
        ushort4 w;
        w.x = f2bf_rn(acc[mf][nf][0] + b);
        w.y = f2bf_rn(acc[mf][nf][1] + b);
        w.z = f2bf_rn(acc[mf][nf][2] + b);
        w.w = f2bf_rn(acc[mf][nf][3] + b);
        *reinterpret_cast<ushort4*>(Vt + (size_t)(h*32 + d)*4096 + rowbase) = w;
      }
    }
}

// ---------------- out-proj GEMM with fused split-K merge ----------------
// grid (2, 32), block 256
__global__ __launch_bounds__(256) void k_gemmo(const float* __restrict__ p0,
    const float* __restrict__ p3, const float* __restrict__ pml,
    const ushort_t* __restrict__ Bh, const ushort_t* __restrict__ Bl,
    const float* __restrict__ bias, float* __restrict__ C)
{
  const int cb = blockIdx.x, rb = blockIdx.y;
  const int g0 = cb*128;
  const int tid = threadIdx.x, wave = tid >> 6, lane = tid & 63;
  const int lrow = lane & 15, lgrp = lane >> 4;
  const int wr = wave >> 1, wc = wave & 1;
  __shared__ __align__(16) ushort_t AswH[128*64];
  __shared__ __align__(16) ushort_t AswL[128*64];
  __shared__ __align__(16) ushort_t BswH[128*64];
  __shared__ __align__(16) ushort_t BswL[128*64];
  const ushort_t* Bhp = Bh + (size_t)g0*256;
  const ushort_t* Blp = Bl + (size_t)g0*256;
  f32x4 acc[4][4];
  #pragma unroll
  for (int m = 0; m < 4; ++m)
    #pragma unroll
    for (int n = 0; n < 4; ++n) acc[m][n] = (f32x4){0.f,0.f,0.f,0.f};

  for (int ks = 0; ks < 4; ++ks) {
    __syncthreads();
    #pragma unroll
    for (int it = 0; it < 8; ++it) {
      const int idx = tid + it*256;
      const int row = rb*128 + (idx >> 4), c4 = idx & 15;
      const int c = ks*64 + c4*4;
      const int h = c >> 5;
      const float den = pml[(size_t)(row*8 + h)*4 + 0] + pml[(size_t)(row*8 + h)*4 + 1]
                      + pml[(size_t)(row*8 + h)*4 + 2] + pml[(size_t)(row*8 + h)*4 + 3];
      const float inv = 1.f / den;
      const size_t bidx = (size_t)row*256 + c;
      float f[4];
      #pragma unroll
      for (int e = 0; e < 4; ++e)
        f[e] = (p0[bidx + e] + p0[1048576 + bidx + e] + p0[2097152 + bidx + e]
              + p3[bidx + e]) * inv;
      ushort_t hi[4], lo[4];
      #pragma unroll
      for (int e = 0; e < 4; ++e) {
        hi[e] = f2bf(f[e]);
        lo[e] = f2bf(f[e] - bf2f(hi[e]));
      }
      const int rloc = idx >> 4;
      const int c8 = c4 >> 1, sub = (c4 & 1) * 4;
      const int off = rloc*64 + ((c8 ^ (rloc & 7)) << 3) + sub;
      *reinterpret_cast<uint2*>(&AswH[off]) = *reinterpret_cast<const uint2*>(hi);
      *reinterpret_cast<uint2*>(&AswL[off]) = *reinterpret_cast<const uint2*>(lo);
    }
    #pragma unroll
    for (int it = 0; it < 4; ++it) {
      const int idx = tid + it*256;
      const int row = idx >> 3, c8 = idx & 7;
      const int off = row*64 + ((c8 ^ (row & 7)) << 3);
      const size_t gsrc = (size_t)row*256 + ks*64 + c8*8;
      *reinterpret_cast<bf16x8*>(&BswH[off]) = *reinterpret_cast<const bf16x8*>(Bhp + gsrc);
      *reinterpret_cast<bf16x8*>(&BswL[off]) = *reinterpret_cast<const bf16x8*>(Blp + gsrc);
    }
    __syncthreads();
    #pragma unroll
    for (int ksub = 0; ksub < 2; ++ksub) {
      bf16x8 ah[4], al[4], bh[4], bl[4];
      const int c8 = ksub*4 + lgrp;
      #pragma unroll
      for (int mf = 0; mf < 4; ++mf) {
        const int row = wr*64 + mf*16 + lrow;
        const int off = row*64 + ((c8 ^ (row & 7)) << 3);
        ah[mf] = *reinterpret_cast<const bf16x8*>(&AswH[off]);
        al[mf] = *reinterpret_cast<const bf16x8*>(&AswL[off]);
      }
      #pragma unroll
      for (int nf = 0; nf < 4; ++nf) {
        const int row = wc*64 + nf*16 + lrow;
        const int off = row*64 + ((c8 ^ (row & 7)) << 3);
        bh[nf] = *reinterpret_cast<const bf16x8*>(&BswH[off]);
        bl[nf] = *reinterpret_cast<const bf16x8*>(&BswL[off]);
      }
      __builtin_amdgcn_s_setprio(1);
      #pragma unroll
      for (int mf = 0; mf < 4; ++mf)
        #pragma unroll
        for (int nf = 0; nf < 4; ++nf) {
          acc[mf][nf] = __builtin_amdgcn_mfma_f32_16x16x32_bf16(ah[mf], bh[nf], acc[mf][nf], 0, 0, 0);
          acc[mf][nf] = __builtin_amdgcn_mfma_f32_16x16x32_bf16(ah[mf], bl[nf], acc[mf][nf], 0, 0, 0);
          acc[mf][nf] = __builtin_amdgcn_mfma_f32_16x16x32_bf16(al[mf], bh[nf], acc[mf][nf], 0, 0, 0);
        }
      __builtin_amdgcn_s_setprio(0);
    }
  }
  float* Cp = C + (size_t)rb*128*256 + g0;
  #pragma unroll
  for (int mf = 0; mf < 4; ++mf)
    #pragma unroll
    for (int nf = 0; nf < 4; ++nf)
      #pragma unroll
      for (int r = 0; r < 4; ++r) {
        const int row = wr*64 + mf*16 + lgrp*4 + r;
        const int col = wc*64 + nf*16 + lrow;
        Cp[(size_t)row*256 + col] = acc[mf][nf][r] + bias[g0 + col];
      }
}

// ---------------- MFMA flash attention: in-register P, XCD-clustered mapping ----------------
// grid 2048 (1-D), block 256 (4 waves x 16 q-rows). No LDS.
// bid = (pair&7) + 8*(qblk*4 + (pair>>3)) so all 64 q-blocks of one (h,sp)
// pair land on one XCD (round-robin dispatch) -> K/V strip stays in that L2.
__global__ __launch_bounds__(256) void k_attn2(const ushort_t* __restrict__ Qh,
    const ushort_t* __restrict__ Kh, const ushort_t* __restrict__ Vt,
    float* __restrict__ pacc, float* __restrict__ pacc3, float* __restrict__ pml)
{
  const int bid = blockIdx.x;
  const int xcd = bid & 7;
  const int rest = bid >> 3;
  const int qblk = rest >> 2;
  const int pair = (rest & 3)*8 + xcd;
  const int h = pair >> 2;
  const int sp = pair & 3;

  const int tid = threadIdx.x;
  const int wave = tid >> 6, lane = tid & 63;
  const int lrow = lane & 15, lgrp = lane >> 4;
  const int q0 = qblk * 64 + wave * 16;

  const int addr1 = (lrow + (((2*lgrp) & 3) << 4)) << 2;
  const int addr2 = (lrow + (((2*lgrp + 1) & 3) << 4)) << 2;
  const bool useA = (lgrp < 2);

  const bf16x8 qf = *reinterpret_cast<const bf16x8*>(
      Qh + ((size_t)(h*4096 + q0 + lrow))*32 + lgrp*8);

  float lsum = 0.f;
  f32x4 o0 = {0.f,0.f,0.f,0.f}, o1 = {0.f,0.f,0.f,0.f};

  const ushort_t* Kbase = Kh + (size_t)(h*4096)*32;
  const ushort_t* Vbase = Vt + (size_t)(h*32)*4096;

  const int kt0 = qblk & 7;   // stagger start phase (order-invariant sums)
  for (int i = 0; i < 8; ++i) {
    const int kt = (kt0 + i) & 7;
    const int kb = sp*1024 + kt*128;
    f32x4 s[8];
    __builtin_amdgcn_s_setprio(1);
    #pragma unroll
    for (int b = 0; b < 8; ++b) {
      const bf16x8 kf = *reinterpret_cast<const bf16x8*>(
          Kbase + (size_t)(kb + b*16 + lrow)*32 + lgrp*8);
      f32x4 z = {0.f,0.f,0.f,0.f};
      s[b] = __builtin_amdgcn_mfma_f32_16x16x32_bf16(kf, qf, z, 0, 0, 0);
    }
    __builtin_amdgcn_s_setprio(0);
    #pragma unroll
    for (int ks2 = 0; ks2 < 4; ++ks2) {
      const f32x4 sa = s[2*ks2], sb = s[2*ks2 + 1];
      const float ea0 = __expf(sa[0]), ea1 = __expf(sa[1]);
      const float ea2 = __expf(sa[2]), ea3 = __expf(sa[3]);
      const float eb0 = __expf(sb[0]), eb1 = __expf(sb[1]);
      const float eb2 = __expf(sb[2]), eb3 = __expf(sb[3]);
      lsum += ((ea0 + ea1) + (ea2 + ea3)) + ((eb0 + eb1) + (eb2 + eb3));
      const int A0 = (int)pkbf(ea0, ea1), A1 = (int)pkbf(ea2, ea3);
      const int B0 = (int)pkbf(eb0, eb1), B1 = (int)pkbf(eb2, eb3);
      const int a0s1 = __builtin_amdgcn_ds_bpermute(addr1, A0);
      const int a1s1 = __builtin_amdgcn_ds_bpermute(addr1, A1);
      const int b0s1 = __builtin_amdgcn_ds_bpermute(addr1, B0);
      const int b1s1 = __builtin_amdgcn_ds_bpermute(addr1, B1);
      const int a0s2 = __builtin_amdgcn_ds_bpermute(addr2, A0);
      const int a1s2 = __builtin_amdgcn_ds_bpermute(addr2, A1);
      const int b0s2 = __builtin_amdgcn_ds_bpermute(addr2, B0);
      const int b1s2 = __builtin_amdgcn_ds_bpermute(addr2, B1);
      union { int u[4]; bf16x8 v; } F;
      F.u[0] = useA ? a0s1 : b0s1;
      F.u[1] = useA ? a1s1 : b1s1;
      F.u[2] = useA ? a0s2 : b0s2;
      F.u[3] = useA ? a1s2 : b1s2;
      const bf16x8 v0 = *reinterpret_cast<const bf16x8*>(
          Vbase + (size_t)lrow*4096 + kb + ks2*32 + lgrp*8);
      const bf16x8 v1 = *reinterpret_cast<const bf16x8*>(
          Vbase + (size_t)(16 + lrow)*4096 + kb + ks2*32 + lgrp*8);
      __builtin_amdgcn_s_setprio(1);
      o0 = __builtin_amdgcn_mfma_f32_16x16x32_bf16(F.v, v0, o0, 0, 0, 0);
      o1 = __builtin_amdgcn_mfma_f32_16x16x32_bf16(F.v, v1, o1, 0, 0, 0);
      __builtin_amdgcn_s_setprio(0);
    }
  }
  float l = lsum;
  l += __shfl_xor(l, 16);
  l += __shfl_xor(l, 32);
  float* po = (sp == 3) ? pacc3 : (pacc + (size_t)sp*1048576);
  #pragma unroll
  for (int r = 0; r < 4; ++r) {
    const int row = q0 + lgrp*4 + r;
    const size_t base = ((size_t)row*8 + h)*32;
    po[base + lrow]      = o0[r];
    po[base + 16 + lrow] = o1[r];
  }
  if (lane < 16) pml[((size_t)(q0 + lrow)*8 + h)*4 + sp] = l;
}

// ---------------- pooling ----------------
__global__ __launch_bounds__(256) void k_pool_logits(const float* __restrict__ z,
    const float* __restrict__ pW, const float* __restrict__ pb, float* __restrict__ logits)
{
  const int tid = threadIdx.x;
  const int wave = tid >> 6, lane = tid & 63;
  const int r = blockIdx.x*4 + wave;
  const float4 zv = reinterpret_cast<const float4*>(z + (size_t)r*256)[lane];
  const float4 wv = reinterpret_cast<const float4*>(pW)[lane];
  float dv = zv.x*wv.x + zv.y*wv.y + zv.z*wv.z + zv.w*wv.w;
  for (int off = 32; off; off >>= 1) dv += __shfl_down(dv, off);
  if (lane == 0) logits[r] = dv + pb[0];
}

// partial with inline stats recompute
__global__ __launch_bounds__(256) void k_pool_partial(const float* __restrict__ z,
    const float* __restrict__ logits, float* __restrict__ partial)
{
  const int pb = blockIdx.x, tid = threadIdx.x;
  __shared__ float rbuf[256];
  __shared__ float wl[64];
  float mx = -1e30f;
  for (int i = tid; i < 4096; i += 256) mx = fmaxf(mx, logits[i]);
  rbuf[tid] = mx; __syncthreads();
  for (int s = 128; s > 0; s >>= 1) { if (tid < s) rbuf[tid] = fmaxf(rbuf[tid], rbuf[tid+s]); __syncthreads(); }
  mx = rbuf[0]; __syncthreads();
  float se = 0.f;
  for (int i = tid; i < 4096; i += 256) se += __expf(logits[i] - mx);
  rbuf[tid] = se; __syncthreads();
  for (int s = 128; s > 0; s >>= 1) { if (tid < s) rbuf[tid] += rbuf[tid+s]; __syncthreads(); }
  se = rbuf[0]; __syncthreads();
  if (tid < 64) wl[tid] = __expf(logits[pb*64 + tid] - mx) / se;
  __syncthreads();
  float acc = 0.f;
  for (int n = 0; n < 64; ++n) acc += wl[n] * z[(size_t)(pb*64 + n)*256 + tid];
  partial[pb*256 + tid] = acc;
}

// ---------------- heads helpers ----------------
__device__ __forceinline__ void mv256(const float* __restrict__ W,
    const float* __restrict__ sIn, float (*red)[256], int o, int hq)
{
  float a0 = 0.f, a1 = 0.f, a2 = 0.f, a3 = 0.f;
  const float* Wp = W + (size_t)(hq*64)*256 + o;
  const float* ip = sIn + hq*64;
  #pragma unroll
  for (int j = 0; j < 16; ++j) {
    a0 += ip[j*4+0] * Wp[(size_t)(j*4+0)*256];
    a1 += ip[j*4+1] * Wp[(size_t)(j*4+1)*256];
    a2 += ip[j*4+2] * Wp[(size_t)(j*4+2)*256];
    a3 += ip[j*4+3] * Wp[(size_t)(j*4+3)*256];
  }
  red[hq][o] = (a0 + a1) + (a2 + a3);
}

// ---------------- heads (single block, 1024 threads) ----------------
__global__ __launch_bounds__(1024) void k_heads(
    const float* __restrict__ partial,
    const float* __restrict__ cx, const float* __restrict__ cW, const float* __restrict__ cb,
    const float* __restrict__ taW1, const float* __restrict__ tab1,
    const float* __restrict__ tag, const float* __restrict__ tabeta,
    const float* __restrict__ taW2, const float* __restrict__ tab2,
    const float* __restrict__ shW1, const float* __restrict__ shb1,
    const float* __restrict__ shW2, const float* __restrict__ shb2,
    const float* __restrict__ fprWa, const float* __restrict__ fprba,
    const float* __restrict__ fprg, const float* __restrict__ fprbeta,
    const float* __restrict__ fprW1, const float* __restrict__ fprb1,
    const float* __restrict__ fprW2, const float* __restrict__ fprb2,
    const float* __restrict__ secW1, const float* __restrict__ secb1,
    const float* __restrict__ secW2, const float* __restrict__ secb2,
    float* __restrict__ out)
{
  const int tid = threadIdx.x;
  const int o = tid & 255, hq = tid >> 8;
  __shared__ float semb[256], esec[256], efpr[256], vbuf[256];
  __shared__ float red[4][256];
  __shared__ float rbuf[256];
  __shared__ float h1s[640];
  float* redf = &red[0][0];

  {
    float acc = 0.f;
    #pragma unroll
    for (int pb = 0; pb < 16; ++pb) acc += partial[(hq*16 + pb)*256 + o];
    #pragma unroll
    for (int i = 0; i < 8; ++i) acc += cx[hq*8 + i] * cW[(hq*8 + i)*256 + o];
    red[hq][o] = acc;
  }
  __syncthreads();
  if (tid < 256) semb[tid] = red[0][tid] + red[1][tid] + red[2][tid] + red[3][tid] + cb[tid];
  __syncthreads();

  for (int i = 0; i < 2; ++i) {
    mv256(taW1 + (size_t)i*65536, semb, red, o, hq);
    __syncthreads();
    float u = 0.f;
    if (tid < 256) u = red[0][tid] + red[1][tid] + red[2][tid] + red[3][tid] + tab1[i*256 + tid];
    if (tid < 256) rbuf[tid] = u;
    __syncthreads();
    for (int s = 128; s > 0; s >>= 1) { if (tid < s) rbuf[tid] += rbuf[tid+s]; __syncthreads(); }
    const float mean = rbuf[0] * (1.f/256.f);
    __syncthreads();
    const float diff = u - mean;
    if (tid < 256) rbuf[tid] = diff*diff;
    __syncthreads();
    for (int s = 128; s > 0; s >>= 1) { if (tid < s) rbuf[tid] += rbuf[tid+s]; __syncthreads(); }
    const float var = rbuf[0] * (1.f/256.f);
    __syncthreads();
    if (tid < 256)
      vbuf[tid] = fmaxf(diff * rsqrtf(var + 1e-5f) * tag[i*256 + tid] + tabeta[i*256 + tid], 0.f);
    __syncthreads();
    mv256(taW2 + (size_t)i*65536, vbuf, red, o, hq);
    __syncthreads();
    if (tid < 256) {
      const float s2v = red[0][tid] + red[1][tid] + red[2][tid] + red[3][tid] + tab2[i*256 + tid];
      const float att = semb[tid] * (1.f/(1.f + __expf(-s2v)));
      if (i == 0) esec[tid] = att; else efpr[tid] = att;
    }
    __syncthreads();
  }

  {
    const int oo = tid & 511, ii = oo >> 7, col = oo & 127, hh = tid >> 9;
    float a0 = 0.f, a1 = 0.f, a2 = 0.f, a3 = 0.f;
    const float* Wp = shW1 + (size_t)ii*32768 + (size_t)(hh*128)*128 + col;
    const float* ip = semb + hh*128;
    #pragma unroll
    for (int j = 0; j < 32; ++j) {
      a0 += ip[j*4+0] * Wp[(size_t)(j*4+0)*128];
      a1 += ip[j*4+1] * Wp[(size_t)(j*4+1)*128];
      a2 += ip[j*4+2] * Wp[(size_t)(j*4+2)*128];
      a3 += ip[j*4+3] * Wp[(size_t)(j*4+3)*128];
    }
    redf[hh*512 + oo] = (a0 + a1) + (a2 + a3);
  }
  __syncthreads();
  if (tid < 512) {
    const int ii = tid >> 7, col = tid & 127;
    h1s[tid] = fmaxf(redf[tid] + redf[512 + tid] + shb1[ii*128 + col], 0.f);
  }
  __syncthreads();
  if (tid < 20) {
    const int ii = tid / 5, c = tid % 5;
    const int rowm = (ii == 0) ? 0 : (ii + 1);
    float ov = shb2[ii*5 + c];
    for (int hh = 0; hh < 128; ++hh) ov += h1s[ii*128 + hh] * shW2[ii*640 + hh*5 + c];
    out[rowm*5 + c] = 1.f/(1.f + __expf(-ov));
  }

  mv256(fprWa, efpr, red, o, hq);
  __syncthreads();
  {
    float u = 0.f;
    if (tid < 256) u = red[0][tid] + red[1][tid] + red[2][tid] + red[3][tid] + fprba[tid];
    if (tid < 256) rbuf[tid] = u;
    __syncthreads();
    for (int s = 128; s > 0; s >>= 1) { if (tid < s) rbuf[tid] += rbuf[tid+s]; __syncthreads(); }
    const float mean = rbuf[0] * (1.f/256.f);
    __syncthreads();
    const float diff = u - mean;
    if (tid < 256) rbuf[tid] = diff*diff;
    __syncthreads();
    for (int s = 128; s > 0; s >>= 1) { if (tid < s) rbuf[tid] += rbuf[tid+s]; __syncthreads(); }
    const float var = rbuf[0] * (1.f/256.f);
    __syncthreads();
    if (tid < 256)
      vbuf[tid] = fmaxf(diff * rsqrtf(var + 1e-5f) * fprg[tid] + fprbeta[tid], 0.f);
    __syncthreads();
  }
  {
    const int col = tid & 127, hs = tid >> 7;
    float a0 = 0.f, a1 = 0.f;
    const float* Wp = fprW1 + (size_t)(hs*32)*128 + col;
    const float* ip = vbuf + hs*32;
    #pragma unroll
    for (int j = 0; j < 16; ++j) {
      a0 += ip[j*2+0] * Wp[(size_t)(j*2+0)*128];
      a1 += ip[j*2+1] * Wp[(size_t)(j*2+1)*128];
    }
    redf[hs*128 + col] = a0 + a1;
  }
  __syncthreads();
  if (tid < 128) {
    float hv = fprb1[tid];
    #pragma unroll
    for (int s = 0; s < 8; ++s) hv += redf[s*128 + tid];
    h1s[tid] = fmaxf(hv, 0.f);
  }
  __syncthreads();
  if (tid < 5) {
    float ov = fprb2[tid];
    for (int hh = 0; hh < 128; ++hh) ov += h1s[hh] * fprW2[hh*5 + tid];
    out[5 + tid] = 1.f/(1.f + __expf(-ov));
  }
  __syncthreads();

  if (tid < 640) {
    const int ii = tid >> 7, col = tid & 127;
    float a0 = 0.f, a1 = 0.f, a2 = 0.f, a3 = 0.f;
    const float* Wp = secW1 + (size_t)ii*32768 + col;
    #pragma unroll
    for (int j = 0; j < 64; ++j) {
      a0 += esec[j*4+0] * Wp[(size_t)(j*4+0)*128];
      a1 += esec[j*4+1] * Wp[(size_t)(j*4+1)*128];
      a2 += esec[j*4+2] * Wp[(size_t)(j*4+2)*128];
      a3 += esec[j*4+3] * Wp[(size_t)(j*4+3)*128];
    }
    h1s[tid] = fmaxf((a0 + a1) + (a2 + a3) + secb1[ii*128 + col], 0.f);
  }
  __syncthreads();
  if (tid < 5) {
    float ov = secb2[tid];
    for (int hh = 0; hh < 128; ++hh) ov += h1s[tid*128 + hh] * secW2[tid*128 + hh];
    out[tid*5 + 1] = 1.f/(1.f + __expf(-ov));
  }
}

// ---------------- launcher ----------------
extern "C" void kernel_launch(void* const* d_in, const int* in_sizes, int n_in,
                              void* d_out, int out_size, void* d_ws, size_t ws_size,
                              hipStream_t stream)
{
  const float* x_nodes    = (const float*)d_in[0];
  const float* contract_x = (const float*)d_in[1];
  const float* proj_W     = (const float*)d_in[2];
  const float* proj_b     = (const float*)d_in[3];
  const float* conv_W     = (const float*)d_in[4];
  const float* conv_b     = (const float*)d_in[5];
  const float* norm_g     = (const float*)d_in[6];
  const float* norm_b     = (const float*)d_in[7];
  const float* attn_W     = (const float*)d_in[8];
  const float* attn_b     = (const float*)d_in[9];
  const float* pool_W     = (const float*)d_in[10];
  const float* pool_b     = (const float*)d_in[11];
  const float* contract_W = (const float*)d_in[12];
  const float* contract_b = (const float*)d_in[13];
  const float* ta_W1      = (const float*)d_in[14];
  const float* ta_b1      = (const float*)d_in[15];
  const float* ta_g       = (const float*)d_in[16];
  const float* ta_beta    = (const float*)d_in[17];
  const float* ta_W2      = (const float*)d_in[18];
  const float* ta_b2      = (const float*)d_in[19];
  const float* sh_W1      = (const float*)d_in[20];
  const float* sh_b1      = (const float*)d_in[21];
  const float* sh_W2      = (const float*)d_in[22];
  const float* sh_b2      = (const float*)d_in[23];
  const float* fpr_Wa     = (const float*)d_in[24];
  const float* fpr_ba     = (const float*)d_in[25];
  const float* fpr_g      = (const float*)d_in[26];
  const float* fpr_beta   = (const float*)d_in[27];
  const float* fpr_W1     = (const float*)d_in[28];
  const float* fpr_b1     = (const float*)d_in[29];
  const float* fpr_W2     = (const float*)d_in[30];
  const float* fpr_b2     = (const float*)d_in[31];
  const float* sec_W1     = (const float*)d_in[32];
  const float* sec_b1     = (const float*)d_in[33];
  const float* sec_W2     = (const float*)d_in[34];
  const float* sec_b2     = (const float*)d_in[35];
  const int*   edge_index = (const int*)d_in[36];

  float* ws = (float*)d_ws;
  float* X     = ws + WS_X;
  float* Y     = ws + WS_Y;
  int*   ints  = (int*)(ws + WS_INT);
  int*   CNTS  = ints + WS_CNTS;
  int*   OFFS  = ints + WS_OFFS;
  int*   CUR   = ints + WS_CUR;
  int*   ELIST = ints + WS_ELIST;
  ushort_t* MHI  = (ushort_t*)(ws + WS_M);
  ushort_t* MLO  = MHI + (size_t)12*1024*256;
  ushort_t* WQHI = (ushort_t*)(ws + WS_WQ);     // 24-matrix half
  ushort_t* WQLO = WQHI + (size_t)24*65536;
  float* PACC  = ws + WS_QKV;                   // sp0..2 (3 x 1M floats)
  float* PACC3 = ws + WS_X;                     // sp3 reuses X region
  float* PML   = ws + WS_PML;
  ushort_t* QH = (ushort_t*)(ws + WS_BF);
  ushort_t* KH = (ushort_t*)(ws + WS_BF + 524288);
  ushort_t* VT = (ushort_t*)(ws + WS_BF + 1048576);
  ushort_t* AWHI = (ushort_t*)(ws + WS_AW);
  ushort_t* AWLO = AWHI + (size_t)4*65536;
  float* PART  = ws + WS_PART;
  float* LOG   = ws + WS_LOG;

  hipMemsetAsync(CNTS, 0, (size_t)K_*NPT_*sizeof(int), stream);

  k_proj<<<dim3(4096), 256, 0, stream>>>(x_nodes, proj_W, proj_b, X);
  k_hist<<<dim3(1536), 256, 0, stream>>>(edge_index, CNTS);
  k_scan<<<dim3(48), 1024, 0, stream>>>(CNTS, OFFS, CUR);
  k_scatter<<<dim3(1536), 256, 0, stream>>>(edge_index, CUR, ELIST);
  k_wprep<<<dim3(4, 8, 8), 256, 0, stream>>>(attn_W, AWHI, AWLO);

  for (int l = 0; l < L_; ++l) {
    for (int half = 0; half < 2; ++half) {
      k_wprep<<<dim3(24, 8, 8), 256, 0, stream>>>(
          conv_W + ((size_t)(l*K_ + half*24))*65536, WQHI, WQLO);
      for (int aa = 0; aa < 2; ++aa) {
        const int a = half*2 + aa;
        k_means<<<dim3(3072), 256, 0, stream>>>(X, OFFS, ELIST, MHI, MLO, a);
        k_wxm<<<dim3(4, 16, 4), 256, 0, stream>>>(MHI, MLO,
            WQHI + (size_t)aa*12*65536, WQLO + (size_t)aa*12*65536, Y, a);
      }
    }
    k_ln<<<dim3(4096), 256, 0, stream>>>(X, Y, CNTS, conv_b, norm_g, norm_b, l);
  }

  // QKV GEMM with fused bf16 cast (writes QH/KH/VT directly)
  k_gemmq<<<dim3(6, 32), 256, 0, stream>>>(X, AWHI, AWLO, attn_b, QH, KH, VT);
  // MFMA flash attention (split-K 4, in-register P, XCD-clustered)
  k_attn2<<<dim3(2048), 256, 0, stream>>>(QH, KH, VT, PACC, PACC3, PML);
  // out projection with fused merge -> z2 in Y
  k_gemmo<<<dim3(2, 32), 256, 0, stream>>>(PACC, PACC3, PML,
      AWHI + (size_t)3*65536, AWLO + (size_t)3*65536, attn_b + 768, Y);
  // pooling (z2 = Y)
  k_pool_logits<<<dim3(1024), 256, 0, stream>>>(Y, pool_W, pool_b, LOG);
  k_pool_partial<<<dim3(64), 256, 0, stream>>>(Y, LOG, PART);
  // heads
  k_heads<<<dim3(1), 1024, 0, stream>>>(PART,
      contract_x, contract_W, contract_b,
      ta_W1, ta_b1, ta_g, ta_beta, ta_W2, ta_b2,
      sh_W1, sh_b1, sh_W2, sh_b2,
      fpr_Wa, fpr_ba, fpr_g, fpr_beta, fpr_W1, fpr_b1, fpr_W2, fpr_b2,
      sec_W1, sec_b1, sec_W2, sec_b2,
      (float*)d_out);
}

// Round 14
// 589.220 us; speedup vs baseline: 1.0431x; 1.0431x over previous
//
#include <hip/hip_runtime.h>
#include <hip/hip_bf16.h>
#include <cstddef>
#include <cstdint>

typedef unsigned short ushort_t;
typedef __attribute__((ext_vector_type(8))) short bf16x8;
typedef __attribute__((ext_vector_type(4))) float f32x4;

// ---------------- constants ----------------
#define H_ 256
#define NPT_ 1024
#define E_ 8192
#define K_ 48
#define L_ 3

// ws layout in floats (~31.3 MB peak)
#define WS_X      0u          // X fp32 [4][1024][256]; pacc sp3 during attn
#define WS_Y      1048576u    // conv GEMM accum / z2 after out-proj
#define WS_INT    2097152u    // int region
#define WS_CNTS   0u
#define WS_OFFS   49152u
#define WS_CUR    98352u
#define WS_ELIST  147504u
#define WS_M      2700288u    // Mhi/Mlo bf16 quarter (3145728 floats)
#define WS_QKV    2700288u    // pacc sp0-2 during attention
#define WS_WQ     5846016u    // conv W HALF hi/lo (1572864 floats)
#define WS_BF     5846016u    // bf16 Q/K/Vt post-conv (same region)
#define WS_PART   7418880u
#define WS_LOG    7435264u
#define WS_STATS  7439360u
#define WS_AW     7440000u    // attn_W hi/lo (262144 floats) -> 7702144
#define WS_PML    7702144u    // attn split l-sums -> 7833216

__device__ __forceinline__ ushort_t f2bf(float x) {
  unsigned u = __float_as_uint(x);
  unsigned r = (u + 0x7FFFu + ((u >> 16) & 1u)) >> 16;
  return (ushort_t)r;
}
__device__ __forceinline__ float bf2f(ushort_t x) {
  return __uint_as_float(((unsigned)x) << 16);
}
__device__ __forceinline__ ushort_t f2bf_rn(float x) {
  __hip_bfloat16 h = __float2bfloat16(x);
  return *reinterpret_cast<ushort_t*>(&h);
}
__device__ __forceinline__ unsigned pkbf(float a, float b) {
  return (unsigned)f2bf_rn(a) | ((unsigned)f2bf_rn(b) << 16);
}

// ---------------- proj ----------------
__global__ __launch_bounds__(256) void k_proj(const float* __restrict__ xn,
    const float* __restrict__ pW, const float* __restrict__ pb,
    float* __restrict__ x)
{
  const int t = blockIdx.x >> 10, n = blockIdx.x & 1023;
  const int tid = threadIdx.x;
  __shared__ float xr[32];
  if (tid < 21) xr[tid] = xn[(size_t)(t*1024 + n)*21 + tid];
  __syncthreads();
  float acc = pb[t*256 + tid];
  #pragma unroll
  for (int i = 0; i < 21; ++i) acc += xr[i] * pW[(size_t)(t*21 + i)*256 + tid];
  x[(size_t)(t*1024 + n)*256 + tid] = acc;
}

// ---------------- fused CSR build: hist + scan + scatter, one block per k ----------------
// grid 48, block 1024. LDS histogram/scan/cursors; writes cnts/offs/elist.
__global__ __launch_bounds__(1024) void k_csr(const int* __restrict__ ei,
    int* __restrict__ cnts, int* __restrict__ offs, int* __restrict__ elist)
{
  const int k = blockIdx.x, tid = threadIdx.x;
  __shared__ int cnt[1024];
  __shared__ int s[1024];
  cnt[tid] = 0;
  __syncthreads();
  // histogram over this k's 8192 edges (LDS atomics)
  #pragma unroll
  for (int it = 0; it < 8; ++it) {
    const int e = tid + it*1024;
    const int dst = ei[(size_t)k*2*E_ + E_ + e];
    atomicAdd(&cnt[dst], 1);
  }
  __syncthreads();
  const int v = cnt[tid];
  cnts[k*1024 + tid] = v;
  s[tid] = v;
  __syncthreads();
  // Hillis-Steele inclusive scan
  for (int off = 1; off < 1024; off <<= 1) {
    int add = 0;
    if (tid >= off) add = s[tid - off];
    __syncthreads();
    s[tid] += add;
    __syncthreads();
  }
  const int ex = s[tid] - v;
  offs[k*1025 + tid] = ex;
  if (tid == 1023) offs[k*1025 + 1024] = s[1023];
  cnt[tid] = ex;                 // reuse cnt[] as scatter cursors
  __syncthreads();
  // scatter
  #pragma unroll
  for (int it = 0; it < 8; ++it) {
    const int e = tid + it*1024;
    const int src = ei[(size_t)k*2*E_ + e];
    const int dst = ei[(size_t)k*2*E_ + E_ + e];
    const int p = atomicAdd(&cnt[dst], 1);
    elist[k*E_ + p] = src;
  }
}

// ---------------- means ----------------
__global__ __launch_bounds__(256) void k_means(const float* __restrict__ X,
    const int* __restrict__ offs, const int* __restrict__ elist,
    ushort_t* __restrict__ Mhi, ushort_t* __restrict__ Mlo, int a)
{
  const int pid = blockIdx.x*4 + (threadIdx.x >> 6);
  const int kl = pid >> 10, d = pid & 1023;
  const int lane = threadIdx.x & 63;
  const int kg = a*12 + kl;
  const int o0 = offs[kg*1025 + d];
  const int o1 = offs[kg*1025 + d + 1];
  const float* xb = X + (size_t)a*1024*256;
  float4 s = {0.f, 0.f, 0.f, 0.f};
  int p = o0;
  while (p + 8 <= o1) {
    int srcs[8];
    #pragma unroll
    for (int q = 0; q < 8; ++q) srcs[q] = elist[(size_t)kg*E_ + p + q];
    float4 v[8];
    #pragma unroll
    for (int q = 0; q < 8; ++q)
      v[q] = *reinterpret_cast<const float4*>(xb + (size_t)srcs[q]*256 + lane*4);
    s.x += ((v[0].x+v[1].x)+(v[2].x+v[3].x)) + ((v[4].x+v[5].x)+(v[6].x+v[7].x));
    s.y += ((v[0].y+v[1].y)+(v[2].y+v[3].y)) + ((v[4].y+v[5].y)+(v[6].y+v[7].y));
    s.z += ((v[0].z+v[1].z)+(v[2].z+v[3].z)) + ((v[4].z+v[5].z)+(v[6].z+v[7].z));
    s.w += ((v[0].w+v[1].w)+(v[2].w+v[3].w)) + ((v[4].w+v[5].w)+(v[6].w+v[7].w));
    p += 8;
  }
  while (p + 4 <= o1) {
    const int s0 = elist[(size_t)kg*E_ + p + 0];
    const int s1 = elist[(size_t)kg*E_ + p + 1];
    const int s2 = elist[(size_t)kg*E_ + p + 2];
    const int s3 = elist[(size_t)kg*E_ + p + 3];
    const float4 v0 = *reinterpret_cast<const float4*>(xb + (size_t)s0*256 + lane*4);
    const float4 v1 = *reinterpret_cast<const float4*>(xb + (size_t)s1*256 + lane*4);
    const float4 v2 = *reinterpret_cast<const float4*>(xb + (size_t)s2*256 + lane*4);
    const float4 v3 = *reinterpret_cast<const float4*>(xb + (size_t)s3*256 + lane*4);
    s.x += (v0.x + v1.x) + (v2.x + v3.x);
    s.y += (v0.y + v1.y) + (v2.y + v3.y);
    s.z += (v0.z + v1.z) + (v2.z + v3.z);
    s.w += (v0.w + v1.w) + (v2.w + v3.w);
    p += 4;
  }
  while (p < o1) {
    const int sp = elist[(size_t)kg*E_ + p];
    const float4 v = *reinterpret_cast<const float4*>(xb + (size_t)sp*256 + lane*4);
    s.x += v.x; s.y += v.y; s.z += v.z; s.w += v.w;
    ++p;
  }
  const float inv = 1.f / fmaxf((float)(o1 - o0), 1.f);
  const float mv[4] = {s.x*inv, s.y*inv, s.z*inv, s.w*inv};
  ushort_t hi[4], lo[4];
  #pragma unroll
  for (int e = 0; e < 4; ++e) {
    hi[e] = f2bf(mv[e]);
    lo[e] = f2bf(mv[e] - bf2f(hi[e]));
  }
  const size_t base = ((size_t)kl*1024 + d)*256 + lane*4;
  *reinterpret_cast<ushort4*>(Mhi + base) = *reinterpret_cast<const ushort4*>(hi);
  *reinterpret_cast<ushort4*>(Mlo + base) = *reinterpret_cast<const ushort4*>(lo);
}

// ---------------- W prep: transpose + hi/lo split ----------------
// grid (nmat, 8, 8), block 256
__global__ __launch_bounds__(256) void k_wprep(const float* __restrict__ Wsrc,
    ushort_t* __restrict__ Whi, ushort_t* __restrict__ Wlo)
{
  const int kl = blockIdx.x, hb = blockIdx.y, gb = blockIdx.z;
  const int tid = threadIdx.x;
  __shared__ float tile[32][33];
  const float* W = Wsrc + (size_t)kl*65536;
  const int r0 = tid >> 5, c = tid & 31;
  #pragma unroll
  for (int it = 0; it < 4; ++it) {
    const int r = it*8 + r0;
    tile[r][c] = W[(size_t)(hb*32 + r)*256 + gb*32 + c];
  }
  __syncthreads();
  #pragma unroll
  for (int it = 0; it < 4; ++it) {
    const int g = it*8 + r0, h = c;
    const float v = tile[h][g];
    const ushort_t hi = f2bf(v);
    const ushort_t lo = f2bf(v - bf2f(hi));
    const size_t off = (size_t)kl*65536 + (size_t)(gb*32 + g)*256 + hb*32 + h;
    Whi[off] = hi;
    Wlo[off] = lo;
  }
}

// ---------------- conv GEMM ----------------
__global__ __launch_bounds__(256) void k_wxm(const ushort_t* __restrict__ Mhi,
    const ushort_t* __restrict__ Mlo, const ushort_t* __restrict__ Wqhi,
    const ushort_t* __restrict__ Wqlo, float* __restrict__ Y, int a)
{
  const int cb = blockIdx.x, rb = blockIdx.y, t = blockIdx.z;
  const int tid = threadIdx.x, wave = tid >> 6, lane = tid & 63;
  const int lrow = lane & 15, lgrp = lane >> 4;
  __shared__ __align__(16) ushort_t AswH[64*64];
  __shared__ __align__(16) ushort_t AswL[64*64];
  __shared__ __align__(16) ushort_t BswH[64*64];
  __shared__ __align__(16) ushort_t BswL[64*64];
  f32x4 acc[4];
  #pragma unroll
  for (int j = 0; j < 4; ++j) acc[j] = (f32x4){0.f,0.f,0.f,0.f};

  for (int c = 0; c < 3; ++c) {
    const int kl = t*3 + c;
    const ushort_t* Ah = Mhi + ((size_t)kl*1024 + rb*64)*256;
    const ushort_t* Al = Mlo + ((size_t)kl*1024 + rb*64)*256;
    const ushort_t* Bh = Wqhi + (size_t)kl*65536 + (size_t)cb*64*256;
    const ushort_t* Bl = Wqlo + (size_t)kl*65536 + (size_t)cb*64*256;
    for (int ks = 0; ks < 4; ++ks) {
      __syncthreads();
      #pragma unroll
      for (int it = 0; it < 2; ++it) {
        const int idx = tid + it*256;
        const int row = idx >> 3, c8 = idx & 7;
        const int off = row*64 + ((c8 ^ (row & 7)) << 3);
        const size_t gsrc = (size_t)row*256 + ks*64 + c8*8;
        *reinterpret_cast<bf16x8*>(&AswH[off]) = *reinterpret_cast<const bf16x8*>(Ah + gsrc);
        *reinterpret_cast<bf16x8*>(&AswL[off]) = *reinterpret_cast<const bf16x8*>(Al + gsrc);
        *reinterpret_cast<bf16x8*>(&BswH[off]) = *reinterpret_cast<const bf16x8*>(Bh + gsrc);
        *reinterpret_cast<bf16x8*>(&BswL[off]) = *reinterpret_cast<const bf16x8*>(Bl + gsrc);
      }
      __syncthreads();
      #pragma unroll
      for (int ksub = 0; ksub < 2; ++ksub) {
        const int c8 = ksub*4 + lgrp;
        const int arow = wave*16 + lrow;
        const int aoff = arow*64 + ((c8 ^ (arow & 7)) << 3);
        const bf16x8 ah = *reinterpret_cast<const bf16x8*>(&AswH[aoff]);
        const bf16x8 al = *reinterpret_cast<const bf16x8*>(&AswL[aoff]);
        #pragma unroll
        for (int nf = 0; nf < 4; ++nf) {
          const int g = nf*16 + lrow;
          const int boff = g*64 + ((c8 ^ (g & 7)) << 3);
          const bf16x8 bh = *reinterpret_cast<const bf16x8*>(&BswH[boff]);
          const bf16x8 bl = *reinterpret_cast<const bf16x8*>(&BswL[boff]);
          __builtin_amdgcn_s_setprio(1);
          acc[nf] = __builtin_amdgcn_mfma_f32_16x16x32_bf16(ah, bh, acc[nf], 0, 0, 0);
          acc[nf] = __builtin_amdgcn_mfma_f32_16x16x32_bf16(ah, bl, acc[nf], 0, 0, 0);
          acc[nf] = __builtin_amdgcn_mfma_f32_16x16x32_bf16(al, bh, acc[nf], 0, 0, 0);
          __builtin_amdgcn_s_setprio(0);
        }
      }
    }
  }
  float* Cb = Y + ((size_t)(t*1024 + rb*64))*256 + cb*64;
  #pragma unroll
  for (int nf = 0; nf < 4; ++nf)
    #pragma unroll
    for (int r = 0; r < 4; ++r) {
      const int row = wave*16 + lgrp*4 + r;
      const int col = nf*16 + lrow;
      if (a == 0) Cb[(size_t)row*256 + col] = acc[nf][r];
      else        Cb[(size_t)row*256 + col] += acc[nf][r];
    }
}

// ---------------- bias-gate + residual + LN + relu ----------------
__global__ __launch_bounds__(256) void k_ln(float* __restrict__ x,
    const float* __restrict__ y, const int* __restrict__ cnts,
    const float* __restrict__ convB, const float* __restrict__ ng,
    const float* __restrict__ nb, int l)
{
  const int r = blockIdx.x;
  const int t = r >> 10, d = r & 1023;
  const int tid = threadIdx.x;
  __shared__ float flag[12];
  __shared__ float rbuf[256];
  if (tid < 12) {
    const int a = tid / 3, c = tid - a*3;
    const int kj = a*12 + t*3 + c;
    flag[tid] = (cnts[kj*1024 + d] > 0) ? 1.f : 0.f;
  }
  __syncthreads();
  float v = y[(size_t)r*256 + tid] + x[(size_t)r*256 + tid];
  #pragma unroll
  for (int j = 0; j < 12; ++j) {
    const int a = j / 3, c = j - a*3;
    const int kj = a*12 + t*3 + c;
    v += flag[j] * convB[(size_t)(l*K_ + kj)*256 + tid];
  }
  rbuf[tid] = v; __syncthreads();
  for (int s = 128; s > 0; s >>= 1) { if (tid < s) rbuf[tid] += rbuf[tid+s]; __syncthreads(); }
  const float mean = rbuf[0] * (1.f/256.f); __syncthreads();
  const float diff = v - mean;
  rbuf[tid] = diff*diff; __syncthreads();
  for (int s = 128; s > 0; s >>= 1) { if (tid < s) rbuf[tid] += rbuf[tid+s]; __syncthreads(); }
  const float var = rbuf[0] * (1.f/256.f); __syncthreads();
  const float xn = diff * rsqrtf(var + 1e-5f) * ng[(size_t)(l*4 + t)*256 + tid]
                 + nb[(size_t)(l*4 + t)*256 + tid];
  x[(size_t)r*256 + tid] = fmaxf(xn, 0.f);
}

// ---------------- QKV GEMM with fused bf16 cast (Q scaled, V transposed) ----------------
// grid (6, 32), block 256
__global__ __launch_bounds__(256) void k_gemmq(const float* __restrict__ A,
    const ushort_t* __restrict__ Bh, const ushort_t* __restrict__ Bl,
    const float* __restrict__ bias,
    ushort_t* __restrict__ Qh, ushort_t* __restrict__ Kh, ushort_t* __restrict__ Vt)
{
  const int cb = blockIdx.x, rb = blockIdx.y;
  const int col0 = cb*128, i = col0 >> 8, g0 = col0 & 255;
  const int tid = threadIdx.x, wave = tid >> 6, lane = tid & 63;
  const int lrow = lane & 15, lgrp = lane >> 4;
  const int wr = wave >> 1, wc = wave & 1;
  __shared__ __align__(16) ushort_t AswH[128*64];
  __shared__ __align__(16) ushort_t AswL[128*64];
  __shared__ __align__(16) ushort_t BswH[128*64];
  __shared__ __align__(16) ushort_t BswL[128*64];
  const float* Ab = A + (size_t)rb*128*256;
  const ushort_t* Bhp = Bh + (size_t)i*65536 + (size_t)g0*256;
  const ushort_t* Blp = Bl + (size_t)i*65536 + (size_t)g0*256;
  f32x4 acc[4][4];
  #pragma unroll
  for (int m = 0; m < 4; ++m)
    #pragma unroll
    for (int n = 0; n < 4; ++n) acc[m][n] = (f32x4){0.f,0.f,0.f,0.f};

  for (int ks = 0; ks < 4; ++ks) {
    __syncthreads();
    #pragma unroll
    for (int it = 0; it < 8; ++it) {
      const int idx = tid + it*256;
      const int row = idx >> 4, c4 = idx & 15;
      const float4 v = *reinterpret_cast<const float4*>(Ab + (size_t)row*256 + ks*64 + c4*4);
      const float f[4] = {v.x, v.y, v.z, v.w};
      ushort_t hi[4], lo[4];
      #pragma unroll
      for (int e = 0; e < 4; ++e) {
        hi[e] = f2bf(f[e]);
        lo[e] = f2bf(f[e] - bf2f(hi[e]));
      }
      const int c8 = c4 >> 1, sub = (c4 & 1) * 4;
      const int off = row*64 + ((c8 ^ (row & 7)) << 3) + sub;
      *reinterpret_cast<uint2*>(&AswH[off]) = *reinterpret_cast<const uint2*>(hi);
      *reinterpret_cast<uint2*>(&AswL[off]) = *reinterpret_cast<const uint2*>(lo);
    }
    #pragma unroll
    for (int it = 0; it < 4; ++it) {
      const int idx = tid + it*256;
      const int row = idx >> 3, c8 = idx & 7;
      const int off = row*64 + ((c8 ^ (row & 7)) << 3);
      const size_t gsrc = (size_t)row*256 + ks*64 + c8*8;
      *reinterpret_cast<bf16x8*>(&BswH[off]) = *reinterpret_cast<const bf16x8*>(Bhp + gsrc);
      *reinterpret_cast<bf16x8*>(&BswL[off]) = *reinterpret_cast<const bf16x8*>(Blp + gsrc);
    }
    __syncthreads();
    #pragma unroll
    for (int ksub = 0; ksub < 2; ++ksub) {
      bf16x8 ah[4], al[4], bh[4], bl[4];
      const int c8 = ksub*4 + lgrp;
      #pragma unroll
      for (int mf = 0; mf < 4; ++mf) {
        const int row = wr*64 + mf*16 + lrow;
        const int off = row*64 + ((c8 ^ (row & 7)) << 3);
        ah[mf] = *reinterpret_cast<const bf16x8*>(&AswH[off]);
        al[mf] = *reinterpret_cast<const bf16x8*>(&AswL[off]);
      }
      #pragma unroll
      for (int nf = 0; nf < 4; ++nf) {
        const int row = wc*64 + nf*16 + lrow;
        const int off = row*64 + ((c8 ^ (row & 7)) << 3);
        bh[nf] = *reinterpret_cast<const bf16x8*>(&BswH[off]);
        bl[nf] = *reinterpret_cast<const bf16x8*>(&BswL[off]);
      }
      __builtin_amdgcn_s_setprio(1);
      #pragma unroll
      for (int mf = 0; mf < 4; ++mf)
        #pragma unroll
        for (int nf = 0; nf < 4; ++nf) {
          acc[mf][nf] = __builtin_amdgcn_mfma_f32_16x16x32_bf16(ah[mf], bh[nf], acc[mf][nf], 0, 0, 0);
          acc[mf][nf] = __builtin_amdgcn_mfma_f32_16x16x32_bf16(ah[mf], bl[nf], acc[mf][nf], 0, 0, 0);
          acc[mf][nf] = __builtin_amdgcn_mfma_f32_16x16x32_bf16(al[mf], bh[nf], acc[mf][nf], 0, 0, 0);
        }
      __builtin_amdgcn_s_setprio(0);
    }
  }
  const float* bp = bias + i*256;
  const float qs = (i == 0) ? 0.17677669529663687f : 1.f;
  #pragma unroll
  for (int mf = 0; mf < 4; ++mf)
    #pragma unroll
    for (int nf = 0; nf < 4; ++nf) {
      const int colg = g0 + wc*64 + nf*16 + lrow;
      const int h = colg >> 5, d = colg & 31;
      const float b = bp[colg];
      const int rowbase = rb*128 + wr*64 + mf*16 + lgrp*4;
      if (i < 2) {
        ushort_t* dst = (i == 0) ? Qh : Kh;
        #pragma unroll
        for (int r = 0; r < 4; ++r)
          dst[((size_t)(h*4096 + rowbase + r))*32 + d] = f2bf_rn((acc[mf][nf][r] + b) * qs);
      } else {
        ushort4 w;
        w.x = f2bf_rn(acc[mf][nf][0] + b);
        w.y = f2bf_rn(acc[mf][nf][1] + b);
        w.z = f2bf_rn(acc[mf][nf][2] + b);
        w.w = f2bf_rn(acc[mf][nf][3] + b);
        *reinterpret_cast<ushort4*>(Vt + (size_t)(h*32 + d)*4096 + rowbase) = w;
      }
    }
}

// ---------------- out-proj GEMM with fused split-K merge ----------------
// grid (2, 32), block 256
__global__ __launch_bounds__(256) void k_gemmo(const float* __restrict__ p0,
    const float* __restrict__ p3, const float* __restrict__ pml,
    const ushort_t* __restrict__ Bh, const ushort_t* __restrict__ Bl,
    const float* __restrict__ bias, float* __restrict__ C)
{
  const int cb = blockIdx.x, rb = blockIdx.y;
  const int g0 = cb*128;
  const int tid = threadIdx.x, wave = tid >> 6, lane = tid & 63;
  const int lrow = lane & 15, lgrp = lane >> 4;
  const int wr = wave >> 1, wc = wave & 1;
  __shared__ __align__(16) ushort_t AswH[128*64];
  __shared__ __align__(16) ushort_t AswL[128*64];
  __shared__ __align__(16) ushort_t BswH[128*64];
  __shared__ __align__(16) ushort_t BswL[128*64];
  const ushort_t* Bhp = Bh + (size_t)g0*256;
  const ushort_t* Blp = Bl + (size_t)g0*256;
  f32x4 acc[4][4];
  #pragma unroll
  for (int m = 0; m < 4; ++m)
    #pragma unroll
    for (int n = 0; n < 4; ++n) acc[m][n] = (f32x4){0.f,0.f,0.f,0.f};

  for (int ks = 0; ks < 4; ++ks) {
    __syncthreads();
    #pragma unroll
    for (int it = 0; it < 8; ++it) {
      const int idx = tid + it*256;
      const int row = rb*128 + (idx >> 4), c4 = idx & 15;
      const int c = ks*64 + c4*4;
      const int h = c >> 5;
      const float den = pml[(size_t)(row*8 + h)*4 + 0] + pml[(size_t)(row*8 + h)*4 + 1]
                      + pml[(size_t)(row*8 + h)*4 + 2] + pml[(size_t)(row*8 + h)*4 + 3];
      const float inv = 1.f / den;
      const size_t bidx = (size_t)row*256 + c;
      float f[4];
      #pragma unroll
      for (int e = 0; e < 4; ++e)
        f[e] = (p0[bidx + e] + p0[1048576 + bidx + e] + p0[2097152 + bidx + e]
              + p3[bidx + e]) * inv;
      ushort_t hi[4], lo[4];
      #pragma unroll
      for (int e = 0; e < 4; ++e) {
        hi[e] = f2bf(f[e]);
        lo[e] = f2bf(f[e] - bf2f(hi[e]));
      }
      const int rloc = idx >> 4;
      const int c8 = c4 >> 1, sub = (c4 & 1) * 4;
      const int off = rloc*64 + ((c8 ^ (rloc & 7)) << 3) + sub;
      *reinterpret_cast<uint2*>(&AswH[off]) = *reinterpret_cast<const uint2*>(hi);
      *reinterpret_cast<uint2*>(&AswL[off]) = *reinterpret_cast<const uint2*>(lo);
    }
    #pragma unroll
    for (int it = 0; it < 4; ++it) {
      const int idx = tid + it*256;
      const int row = idx >> 3, c8 = idx & 7;
      const int off = row*64 + ((c8 ^ (row & 7)) << 3);
      const size_t gsrc = (size_t)row*256 + ks*64 + c8*8;
      *reinterpret_cast<bf16x8*>(&BswH[off]) = *reinterpret_cast<const bf16x8*>(Bhp + gsrc);
      *reinterpret_cast<bf16x8*>(&BswL[off]) = *reinterpret_cast<const bf16x8*>(Blp + gsrc);
    }
    __syncthreads();
    #pragma unroll
    for (int ksub = 0; ksub < 2; ++ksub) {
      bf16x8 ah[4], al[4], bh[4], bl[4];
      const int c8 = ksub*4 + lgrp;
      #pragma unroll
      for (int mf = 0; mf < 4; ++mf) {
        const int row = wr*64 + mf*16 + lrow;
        const int off = row*64 + ((c8 ^ (row & 7)) << 3);
        ah[mf] = *reinterpret_cast<const bf16x8*>(&AswH[off]);
        al[mf] = *reinterpret_cast<const bf16x8*>(&AswL[off]);
      }
      #pragma unroll
      for (int nf = 0; nf < 4; ++nf) {
        const int row = wc*64 + nf*16 + lrow;
        const int off = row*64 + ((c8 ^ (row & 7)) << 3);
        bh[nf] = *reinterpret_cast<const bf16x8*>(&BswH[off]);
        bl[nf] = *reinterpret_cast<const bf16x8*>(&BswL[off]);
      }
      __builtin_amdgcn_s_setprio(1);
      #pragma unroll
      for (int mf = 0; mf < 4; ++mf)
        #pragma unroll
        for (int nf = 0; nf < 4; ++nf) {
          acc[mf][nf] = __builtin_amdgcn_mfma_f32_16x16x32_bf16(ah[mf], bh[nf], acc[mf][nf], 0, 0, 0);
          acc[mf][nf] = __builtin_amdgcn_mfma_f32_16x16x32_bf16(ah[mf], bl[nf], acc[mf][nf], 0, 0, 0);
          acc[mf][nf] = __builtin_amdgcn_mfma_f32_16x16x32_bf16(al[mf], bh[nf], acc[mf][nf], 0, 0, 0);
        }
      __builtin_amdgcn_s_setprio(0);
    }
  }
  float* Cp = C + (size_t)rb*128*256 + g0;
  #pragma unroll
  for (int mf = 0; mf < 4; ++mf)
    #pragma unroll
    for (int nf = 0; nf < 4; ++nf)
      #pragma unroll
      for (int r = 0; r < 4; ++r) {
        const int row = wr*64 + mf*16 + lgrp*4 + r;
        const int col = wc*64 + nf*16 + lrow;
        Cp[(size_t)row*256 + col] = acc[mf][nf][r] + bias[g0 + col];
      }
}

// ---------------- MFMA flash attention: in-register P, XCD-clustered, no setprio ----------------
// grid 2048 (1-D), block 256 (4 waves x 16 q-rows). No LDS.
__global__ __launch_bounds__(256) void k_attn2(const ushort_t* __restrict__ Qh,
    const ushort_t* __restrict__ Kh, const ushort_t* __restrict__ Vt,
    float* __restrict__ pacc, float* __restrict__ pacc3, float* __restrict__ pml)
{
  const int bid = blockIdx.x;
  const int xcd = bid & 7;
  const int rest = bid >> 3;
  const int qblk = rest >> 2;
  const int pair = (rest & 3)*8 + xcd;
  const int h = pair >> 2;
  const int sp = pair & 3;

  const int tid = threadIdx.x;
  const int wave = tid >> 6, lane = tid & 63;
  const int lrow = lane & 15, lgrp = lane >> 4;
  const int q0 = qblk * 64 + wave * 16;

  const int addr1 = (lrow + (((2*lgrp) & 3) << 4)) << 2;
  const int addr2 = (lrow + (((2*lgrp + 1) & 3) << 4)) << 2;
  const bool useA = (lgrp < 2);

  const bf16x8 qf = *reinterpret_cast<const bf16x8*>(
      Qh + ((size_t)(h*4096 + q0 + lrow))*32 + lgrp*8);

  float lsum = 0.f;
  f32x4 o0 = {0.f,0.f,0.f,0.f}, o1 = {0.f,0.f,0.f,0.f};

  const ushort_t* Kbase = Kh + (size_t)(h*4096)*32;
  const ushort_t* Vbase = Vt + (size_t)(h*32)*4096;

  const int kt0 = qblk & 7;   // stagger start phase (order-invariant sums)
  for (int i = 0; i < 8; ++i) {
    const int kt = (kt0 + i) & 7;
    const int kb = sp*1024 + kt*128;
    f32x4 s[8];
    #pragma unroll
    for (int b = 0; b < 8; ++b) {
      const bf16x8 kf = *reinterpret_cast<const bf16x8*>(
          Kbase + (size_t)(kb + b*16 + lrow)*32 + lgrp*8);
      f32x4 z = {0.f,0.f,0.f,0.f};
      s[b] = __builtin_amdgcn_mfma_f32_16x16x32_bf16(kf, qf, z, 0, 0, 0);
    }
    #pragma unroll
    for (int ks2 = 0; ks2 < 4; ++ks2) {
      const f32x4 sa = s[2*ks2], sb = s[2*ks2 + 1];
      const float ea0 = __expf(sa[0]), ea1 = __expf(sa[1]);
      const float ea2 = __expf(sa[2]), ea3 = __expf(sa[3]);
      const float eb0 = __expf(sb[0]), eb1 = __expf(sb[1]);
      const float eb2 = __expf(sb[2]), eb3 = __expf(sb[3]);
      lsum += ((ea0 + ea1) + (ea2 + ea3)) + ((eb0 + eb1) + (eb2 + eb3));
      const int A0 = (int)pkbf(ea0, ea1), A1 = (int)pkbf(ea2, ea3);
      const int B0 = (int)pkbf(eb0, eb1), B1 = (int)pkbf(eb2, eb3);
      const int a0s1 = __builtin_amdgcn_ds_bpermute(addr1, A0);
      const int a1s1 = __builtin_amdgcn_ds_bpermute(addr1, A1);
      const int b0s1 = __builtin_amdgcn_ds_bpermute(addr1, B0);
      const int b1s1 = __builtin_amdgcn_ds_bpermute(addr1, B1);
      const int a0s2 = __builtin_amdgcn_ds_bpermute(addr2, A0);
      const int a1s2 = __builtin_amdgcn_ds_bpermute(addr2, A1);
      const int b0s2 = __builtin_amdgcn_ds_bpermute(addr2, B0);
      const int b1s2 = __builtin_amdgcn_ds_bpermute(addr2, B1);
      union { int u[4]; bf16x8 v; } F;
      F.u[0] = useA ? a0s1 : b0s1;
      F.u[1] = useA ? a1s1 : b1s1;
      F.u[2] = useA ? a0s2 : b0s2;
      F.u[3] = useA ? a1s2 : b1s2;
      const bf16x8 v0 = *reinterpret_cast<const bf16x8*>(
          Vbase + (size_t)lrow*4096 + kb + ks2*32 + lgrp*8);
      const bf16x8 v1 = *reinterpret_cast<const bf16x8*>(
          Vbase + (size_t)(16 + lrow)*4096 + kb + ks2*32 + lgrp*8);
      o0 = __builtin_amdgcn_mfma_f32_16x16x32_bf16(F.v, v0, o0, 0, 0, 0);
      o1 = __builtin_amdgcn_mfma_f32_16x16x32_bf16(F.v, v1, o1, 0, 0, 0);
    }
  }
  float l = lsum;
  l += __shfl_xor(l, 16);
  l += __shfl_xor(l, 32);
  float* po = (sp == 3) ? pacc3 : (pacc + (size_t)sp*1048576);
  #pragma unroll
  for (int r = 0; r < 4; ++r) {
    const int row = q0 + lgrp*4 + r;
    const size_t base = ((size_t)row*8 + h)*32;
    po[base + lrow]      = o0[r];
    po[base + 16 + lrow] = o1[r];
  }
  if (lane < 16) pml[((size_t)(q0 + lrow)*8 + h)*4 + sp] = l;
}

// ---------------- pooling ----------------
__global__ __launch_bounds__(256) void k_pool_logits(const float* __restrict__ z,
    const float* __restrict__ pW, const float* __restrict__ pb, float* __restrict__ logits)
{
  const int tid = threadIdx.x;
  const int wave = tid >> 6, lane = tid & 63;
  const int r = blockIdx.x*4 + wave;
  const float4 zv = reinterpret_cast<const float4*>(z + (size_t)r*256)[lane];
  const float4 wv = reinterpret_cast<const float4*>(pW)[lane];
  float dv = zv.x*wv.x + zv.y*wv.y + zv.z*wv.z + zv.w*wv.w;
  for (int off = 32; off; off >>= 1) dv += __shfl_down(dv, off);
  if (lane == 0) logits[r] = dv + pb[0];
}

// partial with inline stats recompute
__global__ __launch_bounds__(256) void k_pool_partial(const float* __restrict__ z,
    const float* __restrict__ logits, float* __restrict__ partial)
{
  const int pb = blockIdx.x, tid = threadIdx.x;
  __shared__ float rbuf[256];
  __shared__ float wl[64];
  float mx = -1e30f;
  for (int i = tid; i < 4096; i += 256) mx = fmaxf(mx, logits[i]);
  rbuf[tid] = mx; __syncthreads();
  for (int s = 128; s > 0; s >>= 1) { if (tid < s) rbuf[tid] = fmaxf(rbuf[tid], rbuf[tid+s]); __syncthreads(); }
  mx = rbuf[0]; __syncthreads();
  float se = 0.f;
  for (int i = tid; i < 4096; i += 256) se += __expf(logits[i] - mx);
  rbuf[tid] = se; __syncthreads();
  for (int s = 128; s > 0; s >>= 1) { if (tid < s) rbuf[tid] += rbuf[tid+s]; __syncthreads(); }
  se = rbuf[0]; __syncthreads();
  if (tid < 64) wl[tid] = __expf(logits[pb*64 + tid] - mx) / se;
  __syncthreads();
  float acc = 0.f;
  for (int n = 0; n < 64; ++n) acc += wl[n] * z[(size_t)(pb*64 + n)*256 + tid];
  partial[pb*256 + tid] = acc;
}

// ---------------- heads helpers ----------------
__device__ __forceinline__ void mv256(const float* __restrict__ W,
    const float* __restrict__ sIn, float (*red)[256], int o, int hq)
{
  float a0 = 0.f, a1 = 0.f, a2 = 0.f, a3 = 0.f;
  const float* Wp = W + (size_t)(hq*64)*256 + o;
  const float* ip = sIn + hq*64;
  #pragma unroll
  for (int j = 0; j < 16; ++j) {
    a0 += ip[j*4+0] * Wp[(size_t)(j*4+0)*256];
    a1 += ip[j*4+1] * Wp[(size_t)(j*4+1)*256];
    a2 += ip[j*4+2] * Wp[(size_t)(j*4+2)*256];
    a3 += ip[j*4+3] * Wp[(size_t)(j*4+3)*256];
  }
  red[hq][o] = (a0 + a1) + (a2 + a3);
}

// ---------------- heads (single block, 1024 threads) ----------------
__global__ __launch_bounds__(1024) void k_heads(
    const float* __restrict__ partial,
    const float* __restrict__ cx, const float* __restrict__ cW, const float* __restrict__ cb,
    const float* __restrict__ taW1, const float* __restrict__ tab1,
    const float* __restrict__ tag, const float* __restrict__ tabeta,
    const float* __restrict__ taW2, const float* __restrict__ tab2,
    const float* __restrict__ shW1, const float* __restrict__ shb1,
    const float* __restrict__ shW2, const float* __restrict__ shb2,
    const float* __restrict__ fprWa, const float* __restrict__ fprba,
    const float* __restrict__ fprg, const float* __restrict__ fprbeta,
    const float* __restrict__ fprW1, const float* __restrict__ fprb1,
    const float* __restrict__ fprW2, const float* __restrict__ fprb2,
    const float* __restrict__ secW1, const float* __restrict__ secb1,
    const float* __restrict__ secW2, const float* __restrict__ secb2,
    float* __restrict__ out)
{
  const int tid = threadIdx.x;
  const int o = tid & 255, hq = tid >> 8;
  __shared__ float semb[256], esec[256], efpr[256], vbuf[256];
  __shared__ float red[4][256];
  __shared__ float rbuf[256];
  __shared__ float h1s[640];
  float* redf = &red[0][0];

  {
    float acc = 0.f;
    #pragma unroll
    for (int pb = 0; pb < 16; ++pb) acc += partial[(hq*16 + pb)*256 + o];
    #pragma unroll
    for (int i = 0; i < 8; ++i) acc += cx[hq*8 + i] * cW[(hq*8 + i)*256 + o];
    red[hq][o] = acc;
  }
  __syncthreads();
  if (tid < 256) semb[tid] = red[0][tid] + red[1][tid] + red[2][tid] + red[3][tid] + cb[tid];
  __syncthreads();

  for (int i = 0; i < 2; ++i) {
    mv256(taW1 + (size_t)i*65536, semb, red, o, hq);
    __syncthreads();
    float u = 0.f;
    if (tid < 256) u = red[0][tid] + red[1][tid] + red[2][tid] + red[3][tid] + tab1[i*256 + tid];
    if (tid < 256) rbuf[tid] = u;
    __syncthreads();
    for (int s = 128; s > 0; s >>= 1) { if (tid < s) rbuf[tid] += rbuf[tid+s]; __syncthreads(); }
    const float mean = rbuf[0] * (1.f/256.f);
    __syncthreads();
    const float diff = u - mean;
    if (tid < 256) rbuf[tid] = diff*diff;
    __syncthreads();
    for (int s = 128; s > 0; s >>= 1) { if (tid < s) rbuf[tid] += rbuf[tid+s]; __syncthreads(); }
    const float var = rbuf[0] * (1.f/256.f);
    __syncthreads();
    if (tid < 256)
      vbuf[tid] = fmaxf(diff * rsqrtf(var + 1e-5f) * tag[i*256 + tid] + tabeta[i*256 + tid], 0.f);
    __syncthreads();
    mv256(taW2 + (size_t)i*65536, vbuf, red, o, hq);
    __syncthreads();
    if (tid < 256) {
      const float s2v = red[0][tid] + red[1][tid] + red[2][tid] + red[3][tid] + tab2[i*256 + tid];
      const float att = semb[tid] * (1.f/(1.f + __expf(-s2v)));
      if (i == 0) esec[tid] = att; else efpr[tid] = att;
    }
    __syncthreads();
  }

  {
    const int oo = tid & 511, ii = oo >> 7, col = oo & 127, hh = tid >> 9;
    float a0 = 0.f, a1 = 0.f, a2 = 0.f, a3 = 0.f;
    const float* Wp = shW1 + (size_t)ii*32768 + (size_t)(hh*128)*128 + col;
    const float* ip = semb + hh*128;
    #pragma unroll
    for (int j = 0; j < 32; ++j) {
      a0 += ip[j*4+0] * Wp[(size_t)(j*4+0)*128];
      a1 += ip[j*4+1] * Wp[(size_t)(j*4+1)*128];
      a2 += ip[j*4+2] * Wp[(size_t)(j*4+2)*128];
      a3 += ip[j*4+3] * Wp[(size_t)(j*4+3)*128];
    }
    redf[hh*512 + oo] = (a0 + a1) + (a2 + a3);
  }
  __syncthreads();
  if (tid < 512) {
    const int ii = tid >> 7, col = tid & 127;
    h1s[tid] = fmaxf(redf[tid] + redf[512 + tid] + shb1[ii*128 + col], 0.f);
  }
  __syncthreads();
  if (tid < 20) {
    const int ii = tid / 5, c = tid % 5;
    const int rowm = (ii == 0) ? 0 : (ii + 1);
    float ov = shb2[ii*5 + c];
    for (int hh = 0; hh < 128; ++hh) ov += h1s[ii*128 + hh] * shW2[ii*640 + hh*5 + c];
    out[rowm*5 + c] = 1.f/(1.f + __expf(-ov));
  }

  mv256(fprWa, efpr, red, o, hq);
  __syncthreads();
  {
    float u = 0.f;
    if (tid < 256) u = red[0][tid] + red[1][tid] + red[2][tid] + red[3][tid] + fprba[tid];
    if (tid < 256) rbuf[tid] = u;
    __syncthreads();
    for (int s = 128; s > 0; s >>= 1) { if (tid < s) rbuf[tid] += rbuf[tid+s]; __syncthreads(); }
    const float mean = rbuf[0] * (1.f/256.f);
    __syncthreads();
    const float diff = u - mean;
    if (tid < 256) rbuf[tid] = diff*diff;
    __syncthreads();
    for (int s = 128; s > 0; s >>= 1) { if (tid < s) rbuf[tid] += rbuf[tid+s]; __syncthreads(); }
    const float var = rbuf[0] * (1.f/256.f);
    __syncthreads();
    if (tid < 256)
      vbuf[tid] = fmaxf(diff * rsqrtf(var + 1e-5f) * fprg[tid] + fprbeta[tid], 0.f);
    __syncthreads();
  }
  {
    const int col = tid & 127, hs = tid >> 7;
    float a0 = 0.f, a1 = 0.f;
    const float* Wp = fprW1 + (size_t)(hs*32)*128 + col;
    const float* ip = vbuf + hs*32;
    #pragma unroll
    for (int j = 0; j < 16; ++j) {
      a0 += ip[j*2+0] * Wp[(size_t)(j*2+0)*128];
      a1 += ip[j*2+1] * Wp[(size_t)(j*2+1)*128];
    }
    redf[hs*128 + col] = a0 + a1;
  }
  __syncthreads();
  if (tid < 128) {
    float hv = fprb1[tid];
    #pragma unroll
    for (int s = 0; s < 8; ++s) hv += redf[s*128 + tid];
    h1s[tid] = fmaxf(hv, 0.f);
  }
  __syncthreads();
  if (tid < 5) {
    float ov = fprb2[tid];
    for (int hh = 0; hh < 128; ++hh) ov += h1s[hh] * fprW2[hh*5 + tid];
    out[5 + tid] = 1.f/(1.f + __expf(-ov));
  }
  __syncthreads();

  if (tid < 640) {
    const int ii = tid >> 7, col = tid & 127;
    float a0 = 0.f, a1 = 0.f, a2 = 0.f, a3 = 0.f;
    const float* Wp = secW1 + (size_t)ii*32768 + col;
    #pragma unroll
    for (int j = 0; j < 64; ++j) {
      a0 += esec[j*4+0] * Wp[(size_t)(j*4+0)*128];
      a1 += esec[j*4+1] * Wp[(size_t)(j*4+1)*128];
      a2 += esec[j*4+2] * Wp[(size_t)(j*4+2)*128];
      a3 += esec[j*4+3] * Wp[(size_t)(j*4+3)*128];
    }
    h1s[tid] = fmaxf((a0 + a1) + (a2 + a3) + secb1[ii*128 + col], 0.f);
  }
  __syncthreads();
  if (tid < 5) {
    float ov = secb2[tid];
    for (int hh = 0; hh < 128; ++hh) ov += h1s[tid*128 + hh] * secW2[tid*128 + hh];
    out[tid*5 + 1] = 1.f/(1.f + __expf(-ov));
  }
}

// ---------------- launcher ----------------
extern "C" void kernel_launch(void* const* d_in, const int* in_sizes, int n_in,
                              void* d_out, int out_size, void* d_ws, size_t ws_size,
                              hipStream_t stream)
{
  const float* x_nodes    = (const float*)d_in[0];
  const float* contract_x = (const float*)d_in[1];
  const float* proj_W     = (const float*)d_in[2];
  const float* proj_b     = (const float*)d_in[3];
  const float* conv_W     = (const float*)d_in[4];
  const float* conv_b     = (const float*)d_in[5];
  const float* norm_g     = (const float*)d_in[6];
  const float* norm_b     = (const float*)d_in[7];
  const float* attn_W     = (const float*)d_in[8];
  const float* attn_b     = (const float*)d_in[9];
  const float* pool_W     = (const float*)d_in[10];
  const float* pool_b     = (const float*)d_in[11];
  const float* contract_W = (const float*)d_in[12];
  const float* contract_b = (const float*)d_in[13];
  const float* ta_W1      = (const float*)d_in[14];
  const float* ta_b1      = (const float*)d_in[15];
  const float* ta_g       = (const float*)d_in[16];
  const float* ta_beta    = (const float*)d_in[17];
  const float* ta_W2      = (const float*)d_in[18];
  const float* ta_b2      = (const float*)d_in[19];
  const float* sh_W1      = (const float*)d_in[20];
  const float* sh_b1      = (const float*)d_in[21];
  const float* sh_W2      = (const float*)d_in[22];
  const float* sh_b2      = (const float*)d_in[23];
  const float* fpr_Wa     = (const float*)d_in[24];
  const float* fpr_ba     = (const float*)d_in[25];
  const float* fpr_g      = (const float*)d_in[26];
  const float* fpr_beta   = (const float*)d_in[27];
  const float* fpr_W1     = (const float*)d_in[28];
  const float* fpr_b1     = (const float*)d_in[29];
  const float* fpr_W2     = (const float*)d_in[30];
  const float* fpr_b2     = (const float*)d_in[31];
  const float* sec_W1     = (const float*)d_in[32];
  const float* sec_b1     = (const float*)d_in[33];
  const float* sec_W2     = (const float*)d_in[34];
  const float* sec_b2     = (const float*)d_in[35];
  const int*   edge_index = (const int*)d_in[36];

  float* ws = (float*)d_ws;
  float* X     = ws + WS_X;
  float* Y     = ws + WS_Y;
  int*   ints  = (int*)(ws + WS_INT);
  int*   CNTS  = ints + WS_CNTS;
  int*   OFFS  = ints + WS_OFFS;
  int*   ELIST = ints + WS_ELIST;
  ushort_t* MHI  = (ushort_t*)(ws + WS_M);
  ushort_t* MLO  = MHI + (size_t)12*1024*256;
  ushort_t* WQHI = (ushort_t*)(ws + WS_WQ);     // 24-matrix half
  ushort_t* WQLO = WQHI + (size_t)24*65536;
  float* PACC  = ws + WS_QKV;                   // sp0..2 (3 x 1M floats)
  float* PACC3 = ws + WS_X;                     // sp3 reuses X region
  float* PML   = ws + WS_PML;
  ushort_t* QH = (ushort_t*)(ws + WS_BF);
  ushort_t* KH = (ushort_t*)(ws + WS_BF + 524288);
  ushort_t* VT = (ushort_t*)(ws + WS_BF + 1048576);
  ushort_t* AWHI = (ushort_t*)(ws + WS_AW);
  ushort_t* AWLO = AWHI + (size_t)4*65536;
  float* PART  = ws + WS_PART;
  float* LOG   = ws + WS_LOG;

  k_proj<<<dim3(4096), 256, 0, stream>>>(x_nodes, proj_W, proj_b, X);
  k_csr<<<dim3(48), 1024, 0, stream>>>(edge_index, CNTS, OFFS, ELIST);
  k_wprep<<<dim3(4, 8, 8), 256, 0, stream>>>(attn_W, AWHI, AWLO);

  for (int l = 0; l < L_; ++l) {
    for (int half = 0; half < 2; ++half) {
      k_wprep<<<dim3(24, 8, 8), 256, 0, stream>>>(
          conv_W + ((size_t)(l*K_ + half*24))*65536, WQHI, WQLO);
      for (int aa = 0; aa < 2; ++aa) {
        const int a = half*2 + aa;
        k_means<<<dim3(3072), 256, 0, stream>>>(X, OFFS, ELIST, MHI, MLO, a);
        k_wxm<<<dim3(4, 16, 4), 256, 0, stream>>>(MHI, MLO,
            WQHI + (size_t)aa*12*65536, WQLO + (size_t)aa*12*65536, Y, a);
      }
    }
    k_ln<<<dim3(4096), 256, 0, stream>>>(X, Y, CNTS, conv_b, norm_g, norm_b, l);
  }

  // QKV GEMM with fused bf16 cast (writes QH/KH/VT directly)
  k_gemmq<<<dim3(6, 32), 256, 0, stream>>>(X, AWHI, AWLO, attn_b, QH, KH, VT);
  // MFMA flash attention (split-K 4, in-register P, XCD-clustered)
  k_attn2<<<dim3(2048), 256, 0, stream>>>(QH, KH, VT, PACC, PACC3, PML);
  // out projection with fused merge -> z2 in Y
  k_gemmo<<<dim3(2, 32), 256, 0, stream>>>(PACC, PACC3, PML,
      AWHI + (size_t)3*65536, AWLO + (size_t)3*65536, attn_b + 768, Y);
  // pooling (z2 = Y)
  k_pool_logits<<<dim3(1024), 256, 0, stream>>>(Y, pool_W, pool_b, LOG);
  k_pool_partial<<<dim3(64), 256, 0, stream>>>(Y, LOG, PART);
  // heads
  k_heads<<<dim3(1), 1024, 0, stream>>>(PART,
      contract_x, contract_W, contract_b,
      ta_W1, ta_b1, ta_g, ta_beta, ta_W2, ta_b2,
      sh_W1, sh_b1, sh_W2, sh_b2,
      fpr_Wa, fpr_ba, fpr_g, fpr_beta, fpr_W1, fpr_b1, fpr_W2, fpr_b2,
      sec_W1, sec_b1, sec_W2, sec_b2,
      (float*)d_out);
}